// Round 13
// baseline (54.072 us; speedup 1.0000x reference)
//
#include <hip/hip_runtime.h>

#define N2 8192
#define NHALF 4096
#define DDIM 128
#define NCHUNK 16
#define CPC 512           // cols per chunk
#define NT 8              // B-tiles per chunk (512/64)
#define LN2F 0.69314718055994530942f
// SCALEF = sqrt(log2(e)/T) with T=0.5 -> sqrt(2.8853900817779268)
#define SCALEF 1.6986436f

typedef __attribute__((ext_vector_type(8))) short bf8_t;   // 8 bf16 = 4 VGPR
typedef __attribute__((ext_vector_type(4))) float f4_t;    // MFMA C/D frag

__device__ __forceinline__ float fexp2(float x) { return __builtin_amdgcn_exp2f(x); }
__device__ __forceinline__ float flog2(float x) { return __builtin_amdgcn_logf(x); }

__device__ __forceinline__ unsigned short f2bf(float f) {
  unsigned int x = __float_as_uint(f);
  x += 0x7fffu + ((x >> 16) & 1u);   // RNE (no NaN inputs here)
  return (unsigned short)(x >> 16);
}
__device__ __forceinline__ float bf2f(unsigned short h) {
  return __uint_as_float(((unsigned int)h) << 16);
}

// ---------------------------------------------------------------------------
// Kernel 1: normalize rows, scale by sqrt(log2e/T), store bf16 u[8192][128];
// also store dhat[i] = sum_k u_bf16[i][k]^2 (diag logit). Unchanged (passing).
// ---------------------------------------------------------------------------
__global__ __launch_bounds__(256) void knorm(const float* __restrict__ zi,
                                             const float* __restrict__ zj,
                                             unsigned short* __restrict__ u,
                                             float* __restrict__ dhat) {
  const int lane = threadIdx.x & 63;
  const int row = blockIdx.x * 4 + (threadIdx.x >> 6);
  const float* src = (row < NHALF) ? (zi + (size_t)row * DDIM)
                                   : (zj + (size_t)(row - NHALF) * DDIM);
  float2 x = *(const float2*)(src + lane * 2);
  float ss = x.x * x.x + x.y * x.y;
#pragma unroll
  for (int m = 32; m; m >>= 1) ss += __shfl_xor(ss, m);
  float scale = SCALEF / fmaxf(sqrtf(ss), 1e-8f);  // eps clamp as in reference
  unsigned short b0 = f2bf(x.x * scale);
  unsigned short b1 = f2bf(x.y * scale);
  *(unsigned int*)(u + (size_t)row * DDIM + lane * 2) =
      (unsigned int)b0 | ((unsigned int)b1 << 16);
  float f0 = bf2f(b0), f1 = bf2f(b1);
  float dd = f0 * f0 + f1 * f1;
#pragma unroll
  for (int m = 32; m; m >>= 1) dd += __shfl_xor(dd, m);
  if (lane == 0) dhat[row] = dd;
}

// ---------------------------------------------------------------------------
// Kernel 2: fused sim GEMM + per-row sum of exp2 (logits bounded, no max).
// r11/r12 post-mortem: limiter = staged DMA bytes (~290MB at the m97-class
// ~22B/cy/CU global_load_lds rate) + shallow (1-tile) prefetch. Fix:
//  * WG = 256 rows (4 waves x 64 rows, a[4][4] pinned): B-staging 4x lower
//    (64MB B + 32MB A total).
//  * 4-buffer B ring (4 x 16KB), depth-3 prefetch, ONE barrier/tile,
//    counted vmcnt(8) steady state (T3/T4: loads span phases, never drain).
//    Race-free: STAGE(t+3) after COMP(t) writes buf last read at COMP(t-1),
//    which all waves finished before the barrier entering COMP(t).
//  * A staged linearly into the same 64KB region the B-ring reuses (r12
//    validated), frags extracted via swizzled ds_read, pinned.
// Swizzle (validated r11/r12, both-sides involution): 16B-unit d of col c
// stored at d ^ (c&7); reads apply the same XOR -> even 8-quad spread.
// grid = 32 row-blocks x 16 chunks = 512 WGs; LDS 64KB -> 2 WG/CU.
// ---------------------------------------------------------------------------
__global__ __launch_bounds__(256) void ksim(const unsigned short* __restrict__ u,
                                            float* __restrict__ Lp) {
  __shared__ short Bls[32768];  // 64 KB: A-stage, then 4x16KB B ring
  const int tid = threadIdx.x;
  const int lane = tid & 63;
  const int w = tid >> 6;
  const int rb = blockIdx.x >> 4;          // 0..31
  const int chunk = blockIdx.x & 15;       // 0..15
  const int lr = lane & 15, lq = lane >> 4;
  const int rowbase = rb * 256;
  const int colbase = chunk * CPC;

  // ---- A stage: 256 rows = 64KB contiguous, 64 linear DMAs (16 per wave);
  // source pre-swizzled within each 256B row: unit d stored at d^(row&7).
#pragma unroll
  for (int i = 0; i < 16; i++) {
    const int j = w * 16 + i;                      // 1KB block 0..63
    const int row_local = j * 4 + lq;              // 4 rows per block
    const int sdu = lr ^ (4 * (i & 1) + lq);       // (row_local&7) part
    const unsigned short* src =
        u + (size_t)(rowbase + row_local) * DDIM + sdu * 8;
    short* dst = &Bls[j * 512];                    // wave-uniform, linear
    __builtin_amdgcn_global_load_lds(
        (const __attribute__((address_space(1))) unsigned int*)src,
        (__attribute__((address_space(3))) unsigned int*)dst, 16, 0, 0);
  }
  asm volatile("s_waitcnt vmcnt(0)" ::: "memory");
  __builtin_amdgcn_sched_barrier(0);
  __builtin_amdgcn_s_barrier();                    // A staged (all waves)

  // ---- A frag extract (swizzled read), pin in VGPRs (64 rows per wave).
  bf8_t a[4][4];
#pragma unroll
  for (int s = 0; s < 4; s++)
#pragma unroll
    for (int kc = 0; kc < 4; kc++)
      a[s][kc] = *(const bf8_t*)&Bls[(w * 64 + s * 16 + lr) * 128 +
                                     ((kc * 32 + lq * 8) ^ ((lr & 7) << 3))];
#pragma unroll
  for (int s = 0; s < 4; s++)
#pragma unroll
    for (int kc = 0; kc < 4; kc++)
      asm volatile("" : "+v"(a[s][kc]));
  asm volatile("s_waitcnt lgkmcnt(0)" ::: "memory");
  __builtin_amdgcn_sched_barrier(0);
  __builtin_amdgcn_s_barrier();                    // all A-reads done

  f4_t L[4];
#pragma unroll
  for (int s = 0; s < 4; s++) L[s] = (f4_t){0.f, 0.f, 0.f, 0.f};

  // ---- B stage: 64-col tile = 16KB = 16 linear DMAs (4 per wave).
  auto STAGE = [&](int t) {
#pragma unroll
    for (int i = 0; i < 4; i++) {
      const int j = w * 4 + i;                     // 1KB block 0..15
      const int col_local = j * 4 + lq;
      const int sdu = lr ^ (4 * (j & 1) + lq);     // (col&7) part
      const unsigned short* src =
          u + (size_t)(colbase + t * 64 + col_local) * DDIM + sdu * 8;
      short* dst = &Bls[(t & 3) * 8192 + j * 512]; // ring buf, wave-uniform
      __builtin_amdgcn_global_load_lds(
          (const __attribute__((address_space(1))) unsigned int*)src,
          (__attribute__((address_space(3))) unsigned int*)dst, 16, 0, 0);
    }
  };

  auto COMP = [&](int t) {
    const short* P = &Bls[(t & 3) * 8192];
#pragma unroll
    for (int g = 0; g < 4; g++) {
      bf8_t bv[4];
#pragma unroll
      for (int kc = 0; kc < 4; kc++)
        bv[kc] = *(const bf8_t*)&P[(g * 16 + lr) * 128 +
                                   (((kc * 4 + lq) ^ (lr & 7)) * 8)];
      f4_t acc[4];
#pragma unroll
      for (int s = 0; s < 4; s++) acc[s] = (f4_t){0.f, 0.f, 0.f, 0.f};
#pragma unroll
      for (int kc = 0; kc < 4; kc++)
#pragma unroll
        for (int s = 0; s < 4; s++)
          acc[s] = __builtin_amdgcn_mfma_f32_16x16x32_bf16(a[s][kc], bv[kc], acc[s], 0, 0, 0);
#pragma unroll
      for (int s = 0; s < 4; s++)
#pragma unroll
        for (int r = 0; r < 4; r++) L[s][r] += fexp2(acc[s][r]);
    }
  };

  // depth-3 prefetch, 1 barrier per tile, counted vmcnt (steady: 8)
  STAGE(0); STAGE(1); STAGE(2);
#pragma unroll
  for (int t = 0; t < NT; t++) {
    if (t < NT - 2)      asm volatile("s_waitcnt vmcnt(8)" ::: "memory");
    else if (t == NT - 2) asm volatile("s_waitcnt vmcnt(4)" ::: "memory");
    else                 asm volatile("s_waitcnt vmcnt(0)" ::: "memory");
    __builtin_amdgcn_sched_barrier(0);
    __builtin_amdgcn_s_barrier();                  // everyone's tile-t ready
    __builtin_amdgcn_sched_barrier(0);
    COMP(t);
    if (t + 3 < NT) STAGE(t + 3);
  }

  // reduce across the 16 column-lanes (lanes sharing lq hold the same rows)
#pragma unroll
  for (int s = 0; s < 4; s++)
#pragma unroll
    for (int r = 0; r < 4; r++) {
      float v = L[s][r];
      v += __shfl_xor(v, 1); v += __shfl_xor(v, 2);
      v += __shfl_xor(v, 4); v += __shfl_xor(v, 8);
      if (lr == 0)
        Lp[(size_t)chunk * N2 + rowbase + w * 64 + s * 16 + lq * 4 + r] = v;
    }
}

// ---------------------------------------------------------------------------
// Kernel 3: per-row loss. L_i = sum of 16 partials - exp2(dhat_i);
// target logit from direct bf16 dot; loss_i = ln2*(log2(L_i) - target).
// ---------------------------------------------------------------------------
__global__ __launch_bounds__(256) void krow(const unsigned short* __restrict__ u,
                                            const float* __restrict__ dhat,
                                            const float* __restrict__ Lp,
                                            float* __restrict__ bsum) {
  const int i = blockIdx.x * 256 + threadIdx.x;
  float L = 0.f;
#pragma unroll
  for (int c = 0; c < NCHUNK; c++) L += Lp[(size_t)c * N2 + i];
  L -= fexp2(dhat[i]);   // remove self-similarity term (== diag set to -inf)

  const int j = (i + NHALF) & (N2 - 1);  // positive-pair label
  const unsigned int* ui = (const unsigned int*)(u + (size_t)i * DDIM);
  const unsigned int* uj = (const unsigned int*)(u + (size_t)j * DDIM);
  float dot = 0.f;
#pragma unroll
  for (int k = 0; k < DDIM / 2; k++) {
    unsigned int av = ui[k], bv = uj[k];
    dot += __uint_as_float(av << 16) * __uint_as_float(bv << 16) +
           __uint_as_float(av & 0xffff0000u) * __uint_as_float(bv & 0xffff0000u);
  }
  float loss = LN2F * (flog2(L) - dot);

#pragma unroll
  for (int m = 32; m; m >>= 1) loss += __shfl_xor(loss, m);
  __shared__ float sred[4];
  if ((threadIdx.x & 63) == 0) sred[threadIdx.x >> 6] = loss;
  __syncthreads();
  if (threadIdx.x == 0) bsum[blockIdx.x] = sred[0] + sred[1] + sred[2] + sred[3];
}

// ---------------------------------------------------------------------------
// Kernel 4: final mean over the 32 block partials.
// ---------------------------------------------------------------------------
__global__ void kfinal(const float* __restrict__ bsum, float* __restrict__ out) {
  float v = (threadIdx.x < N2 / 256) ? bsum[threadIdx.x] : 0.f;
#pragma unroll
  for (int m = 32; m; m >>= 1) v += __shfl_xor(v, m);
  if (threadIdx.x == 0) out[0] = v * (1.0f / N2);
}

// ---------------------------------------------------------------------------
// ws layout: u bf16 [8192][128] (2 MB) | dhat f32[8192] (32 KB) |
//            Lp f32[NCHUNK][8192] (512 KB) | bsum f32[32]  -> ~2.6 MB total
// ---------------------------------------------------------------------------
extern "C" void kernel_launch(void* const* d_in, const int* in_sizes, int n_in,
                              void* d_out, int out_size, void* d_ws, size_t ws_size,
                              hipStream_t stream) {
  const float* zi = (const float*)d_in[0];
  const float* zj = (const float*)d_in[1];
  char* ws = (char*)d_ws;
  unsigned short* u = (unsigned short*)ws;
  float* dhat = (float*)(ws + (size_t)N2 * DDIM * 2);
  float* Lp = (float*)(ws + (size_t)N2 * DDIM * 2 + (size_t)N2 * 4);
  float* bsum = (float*)(ws + (size_t)N2 * DDIM * 2 + (size_t)N2 * 4 +
                         (size_t)NCHUNK * N2 * 4);
  float* out = (float*)d_out;

  hipLaunchKernelGGL(knorm, dim3(N2 / 4), dim3(256), 0, stream, zi, zj, u, dhat);
  hipLaunchKernelGGL(ksim, dim3((N2 / 256) * NCHUNK), dim3(256), 0, stream, u, Lp);
  hipLaunchKernelGGL(krow, dim3(N2 / 256), dim3(256), 0, stream, u, dhat, Lp, bsum);
  hipLaunchKernelGGL(kfinal, dim3(1), dim3(64), 0, stream, bsum, out);
}

// Round 14
// 40.569 us; speedup vs baseline: 1.3328x; 1.3328x over previous
//
#include <hip/hip_runtime.h>

#define N2 8192
#define NHALF 4096
#define DDIM 128
#define NCHUNK 16
#define CPC 512           // cols per chunk
#define NT 8              // B-tiles per chunk (512/64)
#define LN2F 0.69314718055994530942f
// SCALEF = sqrt(log2(e)/T) with T=0.5 -> sqrt(2.8853900817779268)
#define SCALEF 1.6986436f

typedef __attribute__((ext_vector_type(8))) short bf8_t;   // 8 bf16 = 4 VGPR
typedef __attribute__((ext_vector_type(4))) float f4_t;    // MFMA C/D frag

__device__ __forceinline__ float fexp2(float x) { return __builtin_amdgcn_exp2f(x); }
__device__ __forceinline__ float flog2(float x) { return __builtin_amdgcn_logf(x); }

__device__ __forceinline__ unsigned short f2bf(float f) {
  unsigned int x = __float_as_uint(f);
  x += 0x7fffu + ((x >> 16) & 1u);   // RNE (no NaN inputs here)
  return (unsigned short)(x >> 16);
}
__device__ __forceinline__ float bf2f(unsigned short h) {
  return __uint_as_float(((unsigned int)h) << 16);
}

// ---------------------------------------------------------------------------
// Kernel 1: normalize rows, scale by sqrt(log2e/T), store bf16 u[8192][128];
// also store dhat[i] = sum_k u_bf16[i][k]^2 (diag logit). Unchanged (passing).
// ---------------------------------------------------------------------------
__global__ __launch_bounds__(256) void knorm(const float* __restrict__ zi,
                                             const float* __restrict__ zj,
                                             unsigned short* __restrict__ u,
                                             float* __restrict__ dhat) {
  const int lane = threadIdx.x & 63;
  const int row = blockIdx.x * 4 + (threadIdx.x >> 6);
  const float* src = (row < NHALF) ? (zi + (size_t)row * DDIM)
                                   : (zj + (size_t)(row - NHALF) * DDIM);
  float2 x = *(const float2*)(src + lane * 2);
  float ss = x.x * x.x + x.y * x.y;
#pragma unroll
  for (int m = 32; m; m >>= 1) ss += __shfl_xor(ss, m);
  float scale = SCALEF / fmaxf(sqrtf(ss), 1e-8f);  // eps clamp as in reference
  unsigned short b0 = f2bf(x.x * scale);
  unsigned short b1 = f2bf(x.y * scale);
  *(unsigned int*)(u + (size_t)row * DDIM + lane * 2) =
      (unsigned int)b0 | ((unsigned int)b1 << 16);
  float f0 = bf2f(b0), f1 = bf2f(b1);
  float dd = f0 * f0 + f1 * f1;
#pragma unroll
  for (int m = 32; m; m >>= 1) dd += __shfl_xor(dd, m);
  if (lane == 0) dhat[row] = dd;
}

// ---------------------------------------------------------------------------
// Kernel 2: fused sim GEMM + per-row sum of exp2 (logits bounded, no max).
// r13 post-mortem: geometry (256-row WG, 4x fewer staged B bytes) was right
// but a[4][4]+4-ring+unrolled-if-chain spilled (VGPR=256, WRITE 44MB).
// This round keeps the geometry, removes pressure sources:
//  * A gathered ONCE from global (r3 load pattern), pinned (r5) - no A-stage
//    region, no extract code. One-time TA cost (~32K gathered instrs total).
//  * B: 3-buffer ring (48KB), linear-source global_load_lds with the
//    validated involution pre-swizzle (unit du of col c at du^(c&7)).
//  * ONE barrier/tile + counted vmcnt(4); ring WAR safety: STAGE(t+2) comes
//    after the iter-t barrier, and its buf was last read in COMP(t-1).
//  * Main loop #pragma unroll 1 (r13's unroll multiplied live ranges).
// grid = 32 rowblocks x 16 chunks = 512 WGs; LDS 48KB; no launch_bounds cap.
// ---------------------------------------------------------------------------
__global__ __launch_bounds__(256) void ksim(const unsigned short* __restrict__ u,
                                            float* __restrict__ Lp) {
  __shared__ short Bls[24576];  // 48 KB = 3 ring bufs x 16 KB
  const int tid = threadIdx.x;
  const int lane = tid & 63;
  const int w = tid >> 6;
  const int rb = blockIdx.x >> 4;          // 0..31
  const int chunk = blockIdx.x & 15;       // 0..15
  const int lr = lane & 15, lq = lane >> 4;
  const int rowbase = rb * 256 + w * 64;   // wave's private 64 rows
  const int colbase = chunk * CPC;

  // ---- A: 64 rows per wave, gathered once from global, pinned.
  bf8_t a[4][4];
#pragma unroll
  for (int s = 0; s < 4; s++)
#pragma unroll
    for (int kc = 0; kc < 4; kc++)
      a[s][kc] = *(const bf8_t*)(u + (size_t)(rowbase + s * 16 + lr) * DDIM +
                                 kc * 32 + lq * 8);
#pragma unroll
  for (int s = 0; s < 4; s++)
#pragma unroll
    for (int kc = 0; kc < 4; kc++)
      asm volatile("" : "+v"(a[s][kc]));

  f4_t L[4];
#pragma unroll
  for (int s = 0; s < 4; s++) L[s] = (f4_t){0.f, 0.f, 0.f, 0.f};

  // ---- B stage: 64-col tile = 16KB = 16 linear 1KB DMAs (4 per wave).
  // LDS unit U holds global du = (U&15)^(col&7); lane l of DMA j covers
  // unit j*64+l -> col = j*4+lq, src du = lr^(4*(j&1)+lq).
  auto STAGE = [&](int t) {
    const int bufo = (t % 3) * 8192;                 // shorts
#pragma unroll
    for (int i = 0; i < 4; i++) {
      const int j = w * 4 + i;
      const int col_local = j * 4 + lq;
      const int sdu = lr ^ (4 * (i & 1) + lq);
      const unsigned short* src =
          u + (size_t)(colbase + t * 64 + col_local) * DDIM + sdu * 8;
      short* dst = &Bls[bufo + j * 512];             // wave-uniform, linear
      __builtin_amdgcn_global_load_lds(
          (const __attribute__((address_space(1))) unsigned int*)src,
          (__attribute__((address_space(3))) unsigned int*)dst, 16, 0, 0);
    }
  };

  auto COMP = [&](int t) {
    const short* P = &Bls[(t % 3) * 8192];
#pragma unroll
    for (int g = 0; g < 4; g++) {
      bf8_t bv[4];
#pragma unroll
      for (int kc = 0; kc < 4; kc++)
        bv[kc] = *(const bf8_t*)&P[((g * 16 + lr) * 16 +
                                    ((kc * 4 + lq) ^ (lr & 7))) * 8];
      f4_t acc[4];
#pragma unroll
      for (int s = 0; s < 4; s++) acc[s] = (f4_t){0.f, 0.f, 0.f, 0.f};
#pragma unroll
      for (int kc = 0; kc < 4; kc++)
#pragma unroll
        for (int s = 0; s < 4; s++)
          acc[s] = __builtin_amdgcn_mfma_f32_16x16x32_bf16(a[s][kc], bv[kc], acc[s], 0, 0, 0);
#pragma unroll
      for (int s = 0; s < 4; s++)
#pragma unroll
        for (int r = 0; r < 4; r++) L[s][r] += fexp2(acc[s][r]);
    }
  };

  // depth-2 prefetch, 1 barrier/tile, counted vmcnt (never 0 until the end)
  STAGE(0);
  STAGE(1);
#pragma unroll 1
  for (int t = 0; t < NT; ++t) {
    if (t < NT - 1) {
      asm volatile("s_waitcnt vmcnt(4)" ::: "memory");   // my tile-t DMAs done
    } else {
      asm volatile("s_waitcnt vmcnt(0)" ::: "memory");
    }
    __builtin_amdgcn_sched_barrier(0);
    __builtin_amdgcn_s_barrier();                        // all waves' tile-t done
    __builtin_amdgcn_sched_barrier(0);
    COMP(t);
    if (t + 2 < NT) STAGE(t + 2);
  }

  // reduce across the 16 column-lanes (lanes sharing lq hold the same rows)
#pragma unroll
  for (int s = 0; s < 4; s++)
#pragma unroll
    for (int r = 0; r < 4; r++) {
      float v = L[s][r];
      v += __shfl_xor(v, 1); v += __shfl_xor(v, 2);
      v += __shfl_xor(v, 4); v += __shfl_xor(v, 8);
      if (lr == 0)
        Lp[(size_t)chunk * N2 + rowbase + s * 16 + lq * 4 + r] = v;
    }
}

// ---------------------------------------------------------------------------
// Kernel 3: per-row loss. L_i = sum of 16 partials - exp2(dhat_i);
// target logit from direct bf16 dot; loss_i = ln2*(log2(L_i) - target).
// ---------------------------------------------------------------------------
__global__ __launch_bounds__(256) void krow(const unsigned short* __restrict__ u,
                                            const float* __restrict__ dhat,
                                            const float* __restrict__ Lp,
                                            float* __restrict__ bsum) {
  const int i = blockIdx.x * 256 + threadIdx.x;
  float L = 0.f;
#pragma unroll
  for (int c = 0; c < NCHUNK; c++) L += Lp[(size_t)c * N2 + i];
  L -= fexp2(dhat[i]);   // remove self-similarity term (== diag set to -inf)

  const int j = (i + NHALF) & (N2 - 1);  // positive-pair label
  const unsigned int* ui = (const unsigned int*)(u + (size_t)i * DDIM);
  const unsigned int* uj = (const unsigned int*)(u + (size_t)j * DDIM);
  float dot = 0.f;
#pragma unroll
  for (int k = 0; k < DDIM / 2; k++) {
    unsigned int av = ui[k], bv = uj[k];
    dot += __uint_as_float(av << 16) * __uint_as_float(bv << 16) +
           __uint_as_float(av & 0xffff0000u) * __uint_as_float(bv & 0xffff0000u);
  }
  float loss = LN2F * (flog2(L) - dot);

#pragma unroll
  for (int m = 32; m; m >>= 1) loss += __shfl_xor(loss, m);
  __shared__ float sred[4];
  if ((threadIdx.x & 63) == 0) sred[threadIdx.x >> 6] = loss;
  __syncthreads();
  if (threadIdx.x == 0) bsum[blockIdx.x] = sred[0] + sred[1] + sred[2] + sred[3];
}

// ---------------------------------------------------------------------------
// Kernel 4: final mean over the 32 block partials.
// ---------------------------------------------------------------------------
__global__ void kfinal(const float* __restrict__ bsum, float* __restrict__ out) {
  float v = (threadIdx.x < N2 / 256) ? bsum[threadIdx.x] : 0.f;
#pragma unroll
  for (int m = 32; m; m >>= 1) v += __shfl_xor(v, m);
  if (threadIdx.x == 0) out[0] = v * (1.0f / N2);
}

// ---------------------------------------------------------------------------
// ws layout: u bf16 [8192][128] (2 MB) | dhat f32[8192] (32 KB) |
//            Lp f32[NCHUNK][8192] (512 KB) | bsum f32[32]  -> ~2.6 MB total
// ---------------------------------------------------------------------------
extern "C" void kernel_launch(void* const* d_in, const int* in_sizes, int n_in,
                              void* d_out, int out_size, void* d_ws, size_t ws_size,
                              hipStream_t stream) {
  const float* zi = (const float*)d_in[0];
  const float* zj = (const float*)d_in[1];
  char* ws = (char*)d_ws;
  unsigned short* u = (unsigned short*)ws;
  float* dhat = (float*)(ws + (size_t)N2 * DDIM * 2);
  float* Lp = (float*)(ws + (size_t)N2 * DDIM * 2 + (size_t)N2 * 4);
  float* bsum = (float*)(ws + (size_t)N2 * DDIM * 2 + (size_t)N2 * 4 +
                         (size_t)NCHUNK * N2 * 4);
  float* out = (float*)d_out;

  hipLaunchKernelGGL(knorm, dim3(N2 / 4), dim3(256), 0, stream, zi, zj, u, dhat);
  hipLaunchKernelGGL(ksim, dim3((N2 / 256) * NCHUNK), dim3(256), 0, stream, u, Lp);
  hipLaunchKernelGGL(krow, dim3(N2 / 256), dim3(256), 0, stream, u, dhat, Lp, bsum);
  hipLaunchKernelGGL(kfinal, dim3(1), dim3(64), 0, stream, bsum, out);
}